// Round 1
// baseline (244.963 us; speedup 1.0000x reference)
//
#include <hip/hip_runtime.h>
#include <stdint.h>

#define AS1 __attribute__((address_space(1)))
#define AS3 __attribute__((address_space(3)))

typedef __attribute__((ext_vector_type(8))) short short8;   // 8 bf16 (4 VGPRs) - MFMA A/B frag
typedef __attribute__((ext_vector_type(4))) float f32x4;    // MFMA C/D frag

// B=4, C=384, Q=384, H=256, K=256
// ws layout: [0, 393216)        Wsplit bf16 [3][256][256]  (W_h, W_u, W_hu), [k][h]
//            [393216, 1966080)  term_h fp32 (1536, 256)
//            [1966080, 3538944) term_u fp32 (1536, 256)

__device__ __forceinline__ unsigned int bf16_rne(float f) {
  unsigned int u = __float_as_uint(f);
  u += 0x7FFFu + ((u >> 16) & 1u);   // round-to-nearest-even
  return u >> 16;
}

__device__ __forceinline__ float leaky(float x) { return fmaxf(x, 0.01f * x); }

// ---------------- K0: split w1 (256 x 768 fp32) into 3x 256x256 bf16 ----------------
__global__ void k_convert(const float* __restrict__ w1, unsigned short* __restrict__ ws) {
  int e = blockIdx.x * 256 + threadIdx.x;      // 196608 total
  int k = e / 768;
  int col = e - k * 768;
  ws[((col >> 8) << 16) + (k << 8) + (col & 255)] = (unsigned short)bf16_rne(w1[e]);
}

// ---------------- K1: term_h / term_u GEMM: (1536,256) x (256,256)^T -> fp32 --------
// BM=64, BN=256, BK=32, 256 threads (4 waves, each wave: 64 rows x 64 cols, 4x4 frags)
__global__ void __launch_bounds__(256) k_term(
    const float* __restrict__ hp, const float* __restrict__ up,
    const unsigned short* __restrict__ wsplit,
    float* __restrict__ term_h, float* __restrict__ term_u) {
  const float* x;
  const unsigned short* wsl;
  float* term;
  if (blockIdx.y == 0) { x = hp; wsl = wsplit;         term = term_h; }
  else                 { x = up; wsl = wsplit + 65536; term = term_u; }

  __shared__ __align__(16) unsigned short Ab[64 * 32];
  __shared__ __align__(16) unsigned short Bb[256 * 32];

  const int tid = threadIdx.x;
  const int m0 = blockIdx.x * 64;
  const int w = tid >> 6, l = tid & 63, quad = l >> 4, r = l & 15;
  const int qa = tid >> 2, c4 = tid & 3;

  f32x4 acc[4][4];
#pragma unroll
  for (int i = 0; i < 4; ++i)
#pragma unroll
    for (int j = 0; j < 4; ++j) acc[i][j] = (f32x4){0.f, 0.f, 0.f, 0.f};

  const float* xrow = x + (m0 + qa) * 256 + c4 * 8;
  const int aoff = qa * 32 + ((c4 ^ ((qa >> 1) & 3)) * 8);  // xor-swizzled A slot
  const int rsw = (quad ^ ((r >> 1) & 3)) * 8;              // reader-side swizzle

  for (int h0 = 0; h0 < 256; h0 += 32) {
    float4 v0 = *(const float4*)(xrow + h0);
    float4 v1 = *(const float4*)(xrow + h0 + 4);
#pragma unroll
    for (int s = 0; s < 4; ++s) {
      int chunk = w * 4 + s;
      int krow = chunk * 16 + (l >> 2);
      int ccol = (l & 3) ^ ((krow >> 1) & 3);               // fetch the col that lives at this slot
      const unsigned short* gp = wsl + krow * 256 + h0 + ccol * 8;
      __builtin_amdgcn_global_load_lds((const AS1 void*)gp, (AS3 void*)(Bb + chunk * 512), 16, 0, 0);
    }
    uint4 pk;
    pk.x = bf16_rne(v0.x) | (bf16_rne(v0.y) << 16);
    pk.y = bf16_rne(v0.z) | (bf16_rne(v0.w) << 16);
    pk.z = bf16_rne(v1.x) | (bf16_rne(v1.y) << 16);
    pk.w = bf16_rne(v1.z) | (bf16_rne(v1.w) << 16);
    *(uint4*)&Ab[aoff] = pk;
    __syncthreads();
    short8 a[4], b[4];
#pragma unroll
    for (int i = 0; i < 4; ++i) a[i] = *(const short8*)&Ab[(i * 16 + r) * 32 + rsw];
#pragma unroll
    for (int j = 0; j < 4; ++j) b[j] = *(const short8*)&Bb[(w * 64 + j * 16 + r) * 32 + rsw];
#pragma unroll
    for (int i = 0; i < 4; ++i)
#pragma unroll
      for (int j = 0; j < 4; ++j)
        acc[i][j] = __builtin_amdgcn_mfma_f32_16x16x32_bf16(a[i], b[j], acc[i][j], 0, 0, 0);
    __syncthreads();
  }

  // D mapping (m89-verified): reg ii -> row = quad*4+ii, col = r  (per 16x16 tile)
#pragma unroll
  for (int i = 0; i < 4; ++i) {
    int m = m0 + i * 16 + quad * 4;
#pragma unroll
    for (int ii = 0; ii < 4; ++ii)
#pragma unroll
      for (int j = 0; j < 4; ++j)
        term[(m + ii) * 256 + w * 64 + j * 16 + r] = acc[i][j][ii];
  }
}

// ---------------- K2: main fused kernel ---------------------------------------------
// block = (b, c, q-tile of 64). A[q][h] = h[b,c,h]*u[b,q,h] (bf16), B = W_hu.
// Epilogue fuses layer-2: out[q] = leaky( sum_k leaky(acc+th+tu+b1)*w2[k] + b2 )
__global__ void __launch_bounds__(256) k_main(
    const float* __restrict__ hp, const float* __restrict__ up,
    const unsigned short* __restrict__ whu,
    const float* __restrict__ th, const float* __restrict__ tu,
    const float* __restrict__ b1, const float* __restrict__ w2,
    const float* __restrict__ b2, float* __restrict__ out) {
  __shared__ __align__(16) unsigned short Ab[64 * 32];
  __shared__ __align__(16) unsigned short Bb[256 * 32];
  __shared__ float hrow[256];
  __shared__ float red[64];

  const int tid = threadIdx.x;
  const int blk = blockIdx.x;          // qt + 6*(c + 384*b) -> consecutive blocks share b
  const int qt = blk % 6;
  const int bc = blk / 6;
  const int b = bc / 384;
  const int q0 = qt * 64;

  if (tid < 64) red[tid] = 0.f;
  hrow[tid] = hp[bc * 256 + tid];
  __syncthreads();

  const int w = tid >> 6, l = tid & 63, quad = l >> 4, r = l & 15;
  const int qa = tid >> 2, c4 = tid & 3;

  f32x4 acc[4][4];
#pragma unroll
  for (int i = 0; i < 4; ++i)
#pragma unroll
    for (int j = 0; j < 4; ++j) acc[i][j] = (f32x4){0.f, 0.f, 0.f, 0.f};

  const float* urow = up + (b * 384 + q0 + qa) * 256 + c4 * 8;
  const int aoff = qa * 32 + ((c4 ^ ((qa >> 1) & 3)) * 8);
  const int rsw = (quad ^ ((r >> 1) & 3)) * 8;

  for (int h0 = 0; h0 < 256; h0 += 32) {
    float4 v0 = *(const float4*)(urow + h0);
    float4 v1 = *(const float4*)(urow + h0 + 4);
    float4 g0 = *(const float4*)&hrow[h0 + c4 * 8];
    float4 g1 = *(const float4*)&hrow[h0 + c4 * 8 + 4];
#pragma unroll
    for (int s = 0; s < 4; ++s) {
      int chunk = w * 4 + s;
      int krow = chunk * 16 + (l >> 2);
      int ccol = (l & 3) ^ ((krow >> 1) & 3);
      const unsigned short* gp = whu + krow * 256 + h0 + ccol * 8;
      __builtin_amdgcn_global_load_lds((const AS1 void*)gp, (AS3 void*)(Bb + chunk * 512), 16, 0, 0);
    }
    uint4 pk;
    pk.x = bf16_rne(v0.x * g0.x) | (bf16_rne(v0.y * g0.y) << 16);
    pk.y = bf16_rne(v0.z * g0.z) | (bf16_rne(v0.w * g0.w) << 16);
    pk.z = bf16_rne(v1.x * g1.x) | (bf16_rne(v1.y * g1.y) << 16);
    pk.w = bf16_rne(v1.z * g1.z) | (bf16_rne(v1.w * g1.w) << 16);
    *(uint4*)&Ab[aoff] = pk;
    __syncthreads();
    short8 a[4], bfr[4];
#pragma unroll
    for (int i = 0; i < 4; ++i) a[i] = *(const short8*)&Ab[(i * 16 + r) * 32 + rsw];
#pragma unroll
    for (int j = 0; j < 4; ++j) bfr[j] = *(const short8*)&Bb[(w * 64 + j * 16 + r) * 32 + rsw];
#pragma unroll
    for (int i = 0; i < 4; ++i)
#pragma unroll
      for (int j = 0; j < 4; ++j)
        acc[i][j] = __builtin_amdgcn_mfma_f32_16x16x32_bf16(a[i], bfr[j], acc[i][j], 0, 0, 0);
    __syncthreads();
  }

  // Epilogue: per-lane k values are w*64 + j*16 + r; q rows are q0 + i*16 + quad*4 + ii
  float thb[4], w2k[4];
#pragma unroll
  for (int j = 0; j < 4; ++j) {
    int k = w * 64 + j * 16 + r;
    thb[j] = th[bc * 256 + k] + b1[k];
    w2k[j] = w2[k];
  }
#pragma unroll
  for (int i = 0; i < 4; ++i) {
#pragma unroll
    for (int ii = 0; ii < 4; ++ii) {
      int qloc = i * 16 + quad * 4 + ii;
      const float* tur = tu + (b * 384 + q0 + qloc) * 256;
      float p = 0.f;
#pragma unroll
      for (int j = 0; j < 4; ++j) {
        int k = w * 64 + j * 16 + r;
        float s = acc[i][j][ii] + thb[j] + tur[k];
        p += leaky(s) * w2k[j];
      }
      p += __shfl_xor(p, 1, 64);
      p += __shfl_xor(p, 2, 64);
      p += __shfl_xor(p, 4, 64);
      p += __shfl_xor(p, 8, 64);
      if (r == 0) atomicAdd(&red[qloc], p);   // 4 contributors (k-waves) per q row
    }
  }
  __syncthreads();
  if (tid < 64) {
    float v = red[tid] + b2[0];
    out[bc * 384 + q0 + tid] = leaky(v);
  }
}

extern "C" void kernel_launch(void* const* d_in, const int* in_sizes, int n_in,
                              void* d_out, int out_size, void* d_ws, size_t ws_size,
                              hipStream_t stream) {
  const float* hp = (const float*)d_in[0];   // (4,384,256)
  const float* up = (const float*)d_in[1];   // (4,384,256)
  const float* w1 = (const float*)d_in[2];   // (256,768)
  const float* b1 = (const float*)d_in[3];   // (256,)
  const float* w2 = (const float*)d_in[4];   // (1,256) -> row 0
  const float* b2 = (const float*)d_in[5];   // (1,)
  float* out = (float*)d_out;                // (4,384,384)

  unsigned short* wsplit = (unsigned short*)d_ws;            // 3*65536 bf16
  float* term_h = (float*)((char*)d_ws + 393216);            // (1536,256) f32
  float* term_u = (float*)((char*)d_ws + 1966080);           // (1536,256) f32

  k_convert<<<768, 256, 0, stream>>>(w1, wsplit);
  k_term<<<dim3(24, 2, 1), 256, 0, stream>>>(hp, up, wsplit, term_h, term_u);
  k_main<<<9216, 256, 0, stream>>>(hp, up, wsplit + 2 * 65536, term_h, term_u,
                                   b1, w2, b2, out);
}

// Round 3
// 239.743 us; speedup vs baseline: 1.0218x; 1.0218x over previous
//
#include <hip/hip_runtime.h>
#include <stdint.h>

typedef __attribute__((ext_vector_type(8))) _Float16 half8;  // MFMA f16 A/B frag (4 VGPRs)
typedef __attribute__((ext_vector_type(4))) float f32x4;     // MFMA C/D frag

// B=4, C=384, Q=384, H=256, K=256
// ws: [0, 393216) Wsplit fp16 [3][256][256] = W_h, W_u, W_hu, layout [k][h]
// NOTE: w1 is (K=256 rows, 3H=768 cols): W_m[k][h] = w1[k][m*256 + h]  (axis-0 is k!)

__device__ __forceinline__ float leaky(float x) { return fmaxf(x, 0.01f * x); }

template <int CTRL>
__device__ __forceinline__ float dpp_add(float x) {
  int t = __builtin_amdgcn_update_dpp(0, __float_as_int(x), CTRL, 0xF, 0xF, true);
  return x + __int_as_float(t);
}

// 16-lane sum (within each aligned 16-lane group): xor1, xor2, then +ror4 +ror8
__device__ __forceinline__ float row16_sum(float p) {
  p = dpp_add<0xB1>(p);   // quad_perm(1,0,3,2)  = xor 1
  p = dpp_add<0x4E>(p);   // quad_perm(2,3,0,1)  = xor 2
  p = dpp_add<0x124>(p);  // row_ror:4
  p = dpp_add<0x128>(p);  // row_ror:8  -> full 16-lane sum in every lane
  return p;
}

// ---------------- K0: split w1 (256 k-rows, 768 h-cols) -> fp16 [3][k][h] -----------
__global__ void k_convert(const float* __restrict__ w1, unsigned int* __restrict__ ws) {
  int d = blockIdx.x * 256 + threadIdx.x;        // 98304 dwords (2 fp16 each, along h)
  int m = d >> 15;                               // matrix 0..2
  int rem = d & 32767;
  int k = rem >> 7;
  int h2 = (rem & 127) * 2;
  float x0 = w1[k * 768 + m * 256 + h2];         // w1[k][m*256+h] — axis-0 is k
  float x1 = w1[k * 768 + m * 256 + h2 + 1];
  unsigned short p0 = __builtin_bit_cast(unsigned short, (_Float16)x0);
  unsigned short p1 = __builtin_bit_cast(unsigned short, (_Float16)x1);
  ws[d] = (unsigned int)p0 | ((unsigned int)p1 << 16);
}

// ---------------- K1: fused main kernel ---------------------------------------------
// Block: 32 q-rows x 256 k x 24 c. 256 threads = 4 waves, wave w owns k in [w*64, w*64+64),
// lane (quad,r) holds k = w*64 + 4r + j (j = 0..3)  [consistent permutation everywhere]
// Per c:  pre1[q,k] = sum_h u[q,h]*(h[c,h]*W_hu[k,h] + W_u[k,h]) + (th[c,k]+b1[k])
//         out[q]    = leaky( sum_k leaky(pre1)*w2[k] + b2 )
__global__ void __launch_bounds__(256, 1) k_main(
    const float* __restrict__ hp, const float* __restrict__ up,
    const _Float16* __restrict__ wsp,
    const float* __restrict__ b1, const float* __restrict__ w2,
    const float* __restrict__ b2, float* __restrict__ out) {
  __shared__ __align__(16) float thlds[24 * 256];      // th + b1, fp32, 24 KB
  __shared__ __align__(16) _Float16 hlds[24 * 256];    // h rows, fp16, 12 KB
  __shared__ float redw[2][4][32];

  const int tid = threadIdx.x;
  const int blk = blockIdx.x;            // 768 = 4 b * 12 qt * 16 cc
  const int b = blk / 192;
  const int r0 = blk % 192;
  const int qt = r0 % 12;
  const int cc = r0 / 12;
  const int q0 = qt * 32;
  const int c0 = cc * 24;

  const int w = tid >> 6, l = tid & 63, quad = l >> 4, r = l & 15;
  const int kbase = w * 64 + r * 4;      // lane's 4 k-columns = kbase + j

  const _Float16* Wh = wsp;
  const _Float16* Wu = wsp + 65536;
  const _Float16* Whu = wsp + 131072;

  // ---- stage h rows into LDS as packed fp16, layout [c][h] linear ----
  for (int d = tid; d < 24 * 128; d += 256) {          // 3072 dwords
    int c = d >> 7;
    int hidx = (d & 127) * 2;
    const float* hr = hp + (b * 384 + c0 + c) * 256 + hidx;
    unsigned short p0 = __builtin_bit_cast(unsigned short, (_Float16)hr[0]);
    unsigned short p1 = __builtin_bit_cast(unsigned short, (_Float16)hr[1]);
    ((unsigned int*)hlds)[d] = (unsigned int)p0 | ((unsigned int)p1 << 16);
  }

  // ---- one-time register frags: u (A operand) and W_hu / W_u (B operands) ----
  half8 ufr[2][8];                       // u[q0+i*16+r][s*32+quad*8 .. +8]
#pragma unroll
  for (int i = 0; i < 2; ++i) {
    const float* urow = up + (b * 384 + q0 + i * 16 + r) * 256 + quad * 8;
#pragma unroll
    for (int s = 0; s < 8; ++s) {
      float4 a0 = *(const float4*)(urow + s * 32);
      float4 a1 = *(const float4*)(urow + s * 32 + 4);
      half8 hv;
      hv[0] = (_Float16)a0.x; hv[1] = (_Float16)a0.y;
      hv[2] = (_Float16)a0.z; hv[3] = (_Float16)a0.w;
      hv[4] = (_Float16)a1.x; hv[5] = (_Float16)a1.y;
      hv[6] = (_Float16)a1.z; hv[7] = (_Float16)a1.w;
      ufr[i][s] = hv;
    }
  }
  half8 whu[4][8], wu[4][8];
#pragma unroll
  for (int j = 0; j < 4; ++j) {
    const _Float16* rowu = Whu + (kbase + j) * 256 + quad * 8;
    const _Float16* rowv = Wu + (kbase + j) * 256 + quad * 8;
#pragma unroll
    for (int s = 0; s < 8; ++s) {
      whu[j][s] = *(const half8*)(rowu + s * 32);
      wu[j][s] = *(const half8*)(rowv + s * 32);
    }
  }

  __syncthreads();   // hlds ready

  // ---- prologue MFMA pass: th(+b1) for the block's 24 c-rows -> thlds ----
  f32x4 b1v = *(const f32x4*)(b1 + kbase);
#pragma unroll
  for (int ct = 0; ct < 2; ++ct) {
    f32x4 accq[4];
#pragma unroll
    for (int j = 0; j < 4; ++j) accq[j] = (f32x4){0.f, 0.f, 0.f, 0.f};
#pragma unroll
    for (int s = 0; s < 8; ++s) {
      half8 ha = (half8){};
      if (ct * 16 + r < 24) ha = *(const half8*)&hlds[(ct * 16 + r) * 256 + s * 32 + quad * 8];
#pragma unroll
      for (int j = 0; j < 4; ++j) {
        half8 wb = *(const half8*)(Wh + (kbase + j) * 256 + s * 32 + quad * 8);
        accq[j] = __builtin_amdgcn_mfma_f32_16x16x32_f16(ha, wb, accq[j], 0, 0, 0);
      }
    }
#pragma unroll
    for (int ii = 0; ii < 4; ++ii) {
      int crow = ct * 16 + quad * 4 + ii;
      if (crow < 24) {
        f32x4 v = {accq[0][ii] + b1v[0], accq[1][ii] + b1v[1],
                   accq[2][ii] + b1v[2], accq[3][ii] + b1v[3]};
        *(f32x4*)&thlds[crow * 256 + kbase] = v;
      }
    }
  }
  __syncthreads();   // thlds ready

  // ---- main c-loop: no barriers inside the K-loop ----
  f32x4 w2v = *(const f32x4*)(w2 + kbase);
  f32x4 w2a = w2v * 0.505f;     // leaky(x)*w2 = w2*(0.505x + 0.495|x|)
  f32x4 w2b = w2v * 0.495f;
  const float b2v = b2[0];
  int par = 0;

  for (int c = 0; c < 24; ++c) {
    f32x4 thv = *(const f32x4*)&thlds[c * 256 + kbase];
    f32x4 acc[2][4];
#pragma unroll
    for (int i = 0; i < 2; ++i)
#pragma unroll
      for (int j = 0; j < 4; ++j)
        acc[i][j] = (f32x4){thv[j], thv[j], thv[j], thv[j]};

#pragma unroll
    for (int s = 0; s < 8; ++s) {
      half8 hc = *(const half8*)&hlds[c * 256 + s * 32 + quad * 8];
      half8 bp[4];
#pragma unroll
      for (int j = 0; j < 4; ++j) bp[j] = whu[j][s] * hc + wu[j][s];  // v_pk_fma_f16
#pragma unroll
      for (int i = 0; i < 2; ++i)
#pragma unroll
        for (int j = 0; j < 4; ++j)
          acc[i][j] = __builtin_amdgcn_mfma_f32_16x16x32_f16(ufr[i][s], bp[j], acc[i][j], 0, 0, 0);
    }

    // epilogue: layer-2 dot over k, DPP-reduce over the 16 r-lanes, LDS across waves
#pragma unroll
    for (int i = 0; i < 2; ++i)
#pragma unroll
      for (int ii = 0; ii < 4; ++ii) {
        float p = 0.f;
#pragma unroll
        for (int j = 0; j < 4; ++j) {
          float s = acc[i][j][ii];
          p = fmaf(w2a[j], s, p);
          p = fmaf(w2b[j], fabsf(s), p);
        }
        p = row16_sum(p);
        if (r == 0) redw[par][w][i * 16 + quad * 4 + ii] = p;
      }
    __syncthreads();
    if (tid < 32) {
      float o = redw[par][0][tid] + redw[par][1][tid] + redw[par][2][tid] +
                redw[par][3][tid] + b2v;
      out[(b * 384 + c0 + c) * 384 + q0 + tid] = leaky(o);
    }
    par ^= 1;
  }
}

extern "C" void kernel_launch(void* const* d_in, const int* in_sizes, int n_in,
                              void* d_out, int out_size, void* d_ws, size_t ws_size,
                              hipStream_t stream) {
  const float* hp = (const float*)d_in[0];   // (4,384,256)
  const float* up = (const float*)d_in[1];   // (4,384,256)
  const float* w1 = (const float*)d_in[2];   // (256,768) — axis-0 is k
  const float* b1 = (const float*)d_in[3];   // (256,)
  const float* w2 = (const float*)d_in[4];   // (1,256)
  const float* b2 = (const float*)d_in[5];   // (1,)
  float* out = (float*)d_out;                // (4,384,384)

  unsigned int* wsplit = (unsigned int*)d_ws;   // fp16 [3][256][256]

  k_convert<<<384, 256, 0, stream>>>(w1, wsplit);
  k_main<<<768, 256, 0, stream>>>(hp, up, (const _Float16*)d_ws, b1, w2, b2, out);
}